// Round 1
// baseline (162.528 us; speedup 1.0000x reference)
//
#include <hip/hip_runtime.h>

// Problem constants (fixed shapes from setup_inputs)
constexpr int B  = 8;
constexpr int C  = 32;
constexpr int H  = 224;
constexpr int Wd = 224;
constexpr int ND = 8;   // num_convs
constexpr int K  = 3;
constexpr int Ho = H - K + 1;   // 222
constexpr int Wo = Wd - K + 1;  // 222
constexpr int JG = (Wo + 3) / 4; // 56 column groups of 4

__global__ __launch_bounds__(256)
void dconv_kernel(const float* __restrict__ x,
                  const float* __restrict__ Wt,
                  const float* __restrict__ Bv,
                  float* __restrict__ out) {
    int gid = blockIdx.x * blockDim.x + threadIdx.x;
    // decompose gid -> (b, c, i, jg)
    int jg  = gid % JG;
    int t   = gid / JG;
    int i   = t % Ho;
    t      /= Ho;
    int c   = t % C;
    int b   = t / C;
    if (b >= B) return;

    const int j0 = jg * 4;

    // ---- load 3x6 input patch (reused by all 8 convs) ----
    const float* xp = x + (((long)(b * C + c)) * H + i) * Wd + j0;
    float p[3][6];
#pragma unroll
    for (int r = 0; r < 3; ++r) {
        // x row start is 16B aligned (Wd=224 % 4 == 0), j0 % 4 == 0
        const float4 v4 = *reinterpret_cast<const float4*>(xp + r * Wd);
        p[r][0] = v4.x; p[r][1] = v4.y; p[r][2] = v4.z; p[r][3] = v4.w;
        if (j0 + 4 < Wd) {   // j0 <= 216: cols j0+4, j0+5 in-bounds
            const float2 v2 = *reinterpret_cast<const float2*>(xp + r * Wd + 4);
            p[r][4] = v2.x; p[r][5] = v2.y;
        } else {             // j0 == 220: those columns feed only invalid outputs
            p[r][4] = 0.f;  p[r][5] = 0.f;
        }
    }

    // ---- weights + bias: wave-uniform loads (L1 broadcast / scalarized) ----
    float w[ND][9];
    float bias[ND];
#pragma unroll
    for (int d = 0; d < ND; ++d) {
#pragma unroll
        for (int q = 0; q < 9; ++q) w[d][q] = Wt[d * 9 + q];
        bias[d] = Bv[d];
    }

    const bool full = (j0 + 3 < Wo);  // all 4 columns valid?

    // ---- compute all 8 convs from the in-register patch ----
#pragma unroll
    for (int d = 0; d < ND; ++d) {
        float a0 = bias[d], a1 = bias[d], a2 = bias[d], a3 = bias[d];
#pragma unroll
        for (int r = 0; r < 3; ++r) {
#pragma unroll
            for (int q = 0; q < 3; ++q) {
                const float wv = w[d][r * 3 + q];
                a0 = fmaf(wv, p[r][q + 0], a0);
                a1 = fmaf(wv, p[r][q + 1], a1);
                a2 = fmaf(wv, p[r][q + 2], a2);
                a3 = fmaf(wv, p[r][q + 3], a3);
            }
        }
        float* op = out + ((long)((b * ND + d) * C + c)) * (long)(Ho * Wo)
                        + i * Wo + j0;
        if (full) {
            // 8B-aligned (plane & row strides even, j0 even): two float2 stores
            *reinterpret_cast<float2*>(op + 0) = make_float2(a0, a1);
            *reinterpret_cast<float2*>(op + 2) = make_float2(a2, a3);
        } else {
            // j0 == 220: only 2 valid columns
            op[0] = a0;
            op[1] = a1;
        }
    }
}

extern "C" void kernel_launch(void* const* d_in, const int* in_sizes, int n_in,
                              void* d_out, int out_size, void* d_ws, size_t ws_size,
                              hipStream_t stream) {
    const float* x  = (const float*)d_in[0];
    const float* Wt = (const float*)d_in[1];   // [1, ND, 3, 3] flat
    const float* Bv = (const float*)d_in[2];   // [ND]
    float* out      = (float*)d_out;           // [B, ND*C, Ho, Wo]

    const int total  = B * C * Ho * JG;        // 3,182,592 threads
    const int blocks = (total + 255) / 256;    // 12,432 blocks
    dconv_kernel<<<blocks, 256, 0, stream>>>(x, Wt, Bv, out);
}